// Round 2
// baseline (190.569 us; speedup 1.0000x reference)
//
#include <hip/hip_runtime.h>

// PlateYoloBlock: (32,13,256,256) fp32 -> (32,65536,13) fp32
// out[b][y*256+x][c]:
//   c=0: (sigmoid(v)+x)*8   c=1: (sigmoid(v)+y)*8
//   c=2,3: exp(v)*8         c=4..11: v*8          c=12: sigmoid(v)
//
// R1: latency-bound at 2.4 TB/s (VALUBusy 6%, occ 46%). Fix = float4 loads
// (13 independent dwordx4/thread), register transpose of the 4x13 micro-tile,
// b128 LDS writes, contiguous float4 copy-out.

#define NB      32
#define NC      13
#define HW      65536     // 256*256 positions per batch
#define WIDTH   256
#define TILE    1024      // positions per block (multiple of 4, divides HW)
#define THREADS 256       // each thread owns 4 consecutive positions

__device__ __forceinline__ float sigmoidf_(float x) {
    return 1.0f / (1.0f + __expf(-x));
}

__global__ __launch_bounds__(THREADS) void plate_yolo_kernel(
        const float* __restrict__ in, float* __restrict__ out) {
    __shared__ __align__(16) float lds[TILE * NC];   // 53,248 B -> 3 blocks/CU

    const int tid = threadIdx.x;
    const long long s0 = (long long)blockIdx.x * TILE;   // global spatial base
    const int b = (int)(s0 >> 16);                       // 65536 positions/batch
    const int posBase = (int)(s0 & (HW - 1));
    const float* __restrict__ inB = in + (long long)b * NC * HW + posBase;

    // ---- Stage 1a: 13 independent coalesced dwordx4 loads (4 positions/thread)
    const int p4 = tid * 4;            // local position base
    float4 v[NC];
    #pragma unroll
    for (int c = 0; c < NC; ++c)
        v[c] = *(const float4*)(inB + c * HW + p4);

    // pos..pos+3 stay in one image row: posBase % 1024 == 0, p4 % 4 == 0,
    // (p4 & 255) <= 252 -> x never wraps inside the group of 4.
    const int pos = posBase + p4;
    const float fx0 = (float)(pos & (WIDTH - 1));
    const float fy  = (float)(pos >> 8);

    // ---- Stage 1b: pointwise math + in-register transpose to output order
    float4 o[NC];                      // 52 floats: [pos0 c0..c12][pos1 ...]...
    float* flat = (float*)o;
    #pragma unroll
    for (int j = 0; j < 4; ++j) {
        const float x = fx0 + (float)j;
        #pragma unroll
        for (int c = 0; c < NC; ++c) {
            const float val = ((const float*)&v[c])[j];
            float r;
            if (c == 0)                 r = (sigmoidf_(val) + x) * 8.0f;
            else if (c == 1)            r = (sigmoidf_(val) + fy) * 8.0f;
            else if (c == 2 || c == 3)  r = __expf(val) * 8.0f;
            else if (c == 12)           r = sigmoidf_(val);
            else                        r = val * 8.0f;
            flat[j * NC + c] = r;
        }
    }

    // ---- Stage 1c: 13 x ds_write_b128, thread stride 208 B (16B-aligned).
    // Banks: starts cycle {0,4,...,28} -> all 32 banks, 8 phases = b128 minimum.
    float4* ldsBase = (float4*)(lds + tid * (4 * NC));
    #pragma unroll
    for (int q = 0; q < NC; ++q)
        ldsBase[q] = o[q];

    __syncthreads();

    // ---- Stage 2: contiguous float4 copy-out (ds_read_b128 + store_dwordx4).
    // TILE*NC/4 = 3328 = 13 * THREADS -> exactly 13 uniform iterations.
    const float4* __restrict__ src = (const float4*)lds;
    float4* __restrict__ dst = (float4*)(out + s0 * NC);
    #pragma unroll
    for (int j = 0; j < NC; ++j)
        dst[j * THREADS + tid] = src[j * THREADS + tid];
}

extern "C" void kernel_launch(void* const* d_in, const int* in_sizes, int n_in,
                              void* d_out, int out_size, void* d_ws, size_t ws_size,
                              hipStream_t stream) {
    const float* in = (const float*)d_in[0];
    float* out = (float*)d_out;
    const int blocks = (NB * HW) / TILE;   // 2048
    plate_yolo_kernel<<<blocks, THREADS, 0, stream>>>(in, out);
}